// Round 2
// baseline (1793.553 us; speedup 1.0000x reference)
//
#include <hip/hip_runtime.h>
#include <hip/hip_bf16.h>
#include <math.h>

#define L_SEQ 8192
#define NFFT  16384
#define F_DIM 768
#define D_DIM 768
#define C_IN  2304   // INNER = F*(ORDER+1)
#define NORD  2

// ===========================================================================
// Radix-4 FFT over LDS, N = 16384 = 4^7.
// fwd: DIF, natural-order input -> base-4 digit-reversed output.
// inv: DIT, digit-reversed input -> natural output, UNNORMALIZED (= N * ifft).
// Filter spectra are produced by the same fwd routine, so pointwise products
// line up positionally; inv consumes exactly fwd's output order.
// ===========================================================================
template<int NT>
__device__ __forceinline__ void fft4_fwd(float* zr, float* zi, int tid)
{
  for (int lq = 12; lq >= 0; lq -= 2) {
    const int q = 1 << lq;
    const float stw = -6.2831853071795864769f / (float)(q << 2);
    for (int b = tid; b < NFFT / 4; b += NT) {
      const int j = b & (q - 1);
      const int base = ((b >> lq) << (lq + 2)) + j;
      float a0r = zr[base        ], a0i = zi[base        ];
      float a1r = zr[base +     q], a1i = zi[base +     q];
      float a2r = zr[base + 2 * q], a2i = zi[base + 2 * q];
      float a3r = zr[base + 3 * q], a3i = zi[base + 3 * q];
      float t0r = a0r + a2r, t0i = a0i + a2i;
      float t1r = a0r - a2r, t1i = a0i - a2i;
      float t2r = a1r + a3r, t2i = a1i + a3i;
      float t3r = a1r - a3r, t3i = a1i - a3i;
      float y0r = t0r + t2r, y0i = t0i + t2i;
      float y1r = t1r + t3i, y1i = t1i - t3r;   // B1 = t1 - i*t3
      float y2r = t0r - t2r, y2i = t0i - t2i;   // B2 = t0 - t2
      float y3r = t1r - t3i, y3i = t1i + t3r;   // B3 = t1 + i*t3
      float ang = stw * (float)j;
      float s1, c1; __sincosf(ang, &s1, &c1);
      float c2 = c1 * c1 - s1 * s1, s2 = 2.0f * c1 * s1;
      float c3 = c1 * c2 - s1 * s2, s3 = c1 * s2 + s1 * c2;
      zr[base        ] = y0r;
      zi[base        ] = y0i;
      zr[base +     q] = y1r * c1 - y1i * s1;
      zi[base +     q] = y1r * s1 + y1i * c1;
      zr[base + 2 * q] = y2r * c2 - y2i * s2;
      zi[base + 2 * q] = y2r * s2 + y2i * c2;
      zr[base + 3 * q] = y3r * c3 - y3i * s3;
      zi[base + 3 * q] = y3r * s3 + y3i * c3;
    }
    __syncthreads();
  }
}

template<int NT>
__device__ __forceinline__ void fft4_inv(float* zr, float* zi, int tid)
{
  for (int lq = 0; lq <= 12; lq += 2) {
    const int q = 1 << lq;
    const float stw = 6.2831853071795864769f / (float)(q << 2);
    for (int b = tid; b < NFFT / 4; b += NT) {
      const int j = b & (q - 1);
      const int base = ((b >> lq) << (lq + 2)) + j;
      float u0r = zr[base        ], u0i = zi[base        ];
      float z1r = zr[base +     q], z1i = zi[base +     q];
      float z2r = zr[base + 2 * q], z2i = zi[base + 2 * q];
      float z3r = zr[base + 3 * q], z3i = zi[base + 3 * q];
      float ang = stw * (float)j;
      float s1, c1; __sincosf(ang, &s1, &c1);
      float c2 = c1 * c1 - s1 * s1, s2 = 2.0f * c1 * s1;
      float c3 = c1 * c2 - s1 * s2, s3 = c1 * s2 + s1 * c2;
      float u1r = z1r * c1 - z1i * s1, u1i = z1r * s1 + z1i * c1;
      float u2r = z2r * c2 - z2i * s2, u2i = z2r * s2 + z2i * c2;
      float u3r = z3r * c3 - z3i * s3, u3i = z3r * s3 + z3i * c3;
      float e0r = u0r + u2r, e0i = u0i + u2i;
      float e1r = u0r - u2r, e1i = u0i - u2i;
      float f0r = u1r + u3r, f0i = u1i + u3i;
      float f1r = u1r - u3r, f1i = u1i - u3i;
      zr[base        ] = e0r + f0r; zi[base        ] = e0i + f0i; // u0+u1+u2+u3
      zr[base +     q] = e1r - f1i; zi[base +     q] = e1i + f1r; // e1 + i*f1
      zr[base + 2 * q] = e0r - f0r; zi[base + 2 * q] = e0i - f0i; // e0 - f0
      zr[base + 3 * q] = e1r + f1i; zi[base + 3 * q] = e1i - f1r; // e1 - i*f1
    }
    __syncthreads();
  }
}

// depthwise conv3, SAME padding (XLA cross-correlation convention: no flip)
__device__ __forceinline__ float conv3(const float* __restrict__ row, int t,
                                       float w0, float w1, float w2, float sb)
{
  float l = (t > 0)         ? row[t - 1] : 0.0f;
  float r = (t < L_SEQ - 1) ? row[t + 1] : 0.0f;
  return w0 * l + w1 * row[t] + w2 * r + sb;
}

// ===========================================================================
// Kernel A: filter MLP -> h_t[(o*768+f)][tau], tau in [0,16384), fp32
// ===========================================================================
__global__ __launch_bounds__(256)
void filter_gen_kernel(const float* __restrict__ w1, const float* __restrict__ b1,
                       const float* __restrict__ w2, const float* __restrict__ b2,
                       const float* __restrict__ decay, float* __restrict__ h_t)
{
  __shared__ float hid[64][65];
  const int tid  = threadIdx.x;
  const int tau0 = blockIdx.x * 64;
  const int c0   = blockIdx.y * 256;

  { // hidden features for this tau tile (64 tau x 64 r)
    const int r = tid & 63;
    const int tb = tid >> 6;
    const float w1v0 = w1[r];
    const float b1v = b1[r];
    float w1c[4], w1s[4];
    #pragma unroll
    for (int p = 0; p < 4; ++p) { w1c[p] = w1[(1 + p) * 64 + r]; w1s[p] = w1[(5 + p) * 64 + r]; }
    #pragma unroll
    for (int i = 0; i < 16; ++i) {
      const int tl = tb + i * 4;
      const int tau = tau0 + tl;
      const float off = (tau < L_SEQ) ? (float)tau : (float)(tau - NFFT);
      float acc = b1v + off * (1.0f / 8192.0f) * w1v0;
      #pragma unroll
      for (int p = 0; p < 4; ++p) {
        const double period = 4.0 + (8188.0 * p) / 3.0;   // linspace(4, 8192, 4)
        const float freq = (float)(6.283185307179586476925287 / period);
        float sp, cp;
        sincosf(off * freq, &sp, &cp);                    // accurate arg reduction
        acc += cp * w1c[p] + sp * w1s[p];
      }
      hid[r][tl] = sinf(acc);
    }
  }
  __syncthreads();

  const int tx = tid & 63;        // tau lane (coalesced writes)
  const int ty = tid >> 6;        // c block selector
  const int taug = tau0 + tx;
  const float mt = (taug < L_SEQ) ? (float)taug * (1.0f / 8191.0f)
                                  : (float)(NFFT - 1 - taug) * (1.0f / 8191.0f);
  const int cbase = c0 + ty * 64;
  for (int cb = 0; cb < 8; ++cb) {
    const int c8 = cbase + cb * 8;
    float acc[8];
    #pragma unroll
    for (int jj = 0; jj < 8; ++jj) acc[jj] = b2[c8 + jj];
    for (int rr = 0; rr < 64; ++rr) {
      const float hv = hid[rr][tx];
      const float4 wa = *(const float4*)&w2[rr * 1536 + c8];
      const float4 wb = *(const float4*)&w2[rr * 1536 + c8 + 4];
      acc[0] += hv * wa.x; acc[1] += hv * wa.y; acc[2] += hv * wa.z; acc[3] += hv * wa.w;
      acc[4] += hv * wb.x; acc[5] += hv * wb.y; acc[6] += hv * wb.z; acc[7] += hv * wb.w;
    }
    #pragma unroll
    for (int jj = 0; jj < 8; ++jj) {
      const int c = c8 + jj;
      const float dec = __expf(-mt * fabsf(decay[c]));
      h_t[(size_t)c * NFFT + taug] = acc[jj] * dec;
    }
  }
}

// ===========================================================================
// Kernel B: filter spectra, IN PLACE. Row r (16384 fp32) is replaced by its
// spectrum as 16384 x (bf16 re, bf16 im) -- same 64 KB footprint, so no
// separate Hs region (this was the d_ws overflow in round 1).
// Bias folding: y + v*bias == conv(v, h + bias*delta0); delta0's spectrum is
// the constant `bias` in every bin (permutation-independent).
// ===========================================================================
__global__ __launch_bounds__(512)
void filter_fft_kernel(float* __restrict__ hH, const float* __restrict__ bias)
{
  __shared__ float zr[NFFT];
  __shared__ float zi[NFFT];
  const int row = blockIdx.x;          // o*768 + f
  const int tid = threadIdx.x;
  float* h = hH + (size_t)row * NFFT;
  for (int t = tid; t < NFFT; t += 512) { zr[t] = h[t]; zi[t] = 0.0f; }
  __syncthreads();
  fft4_fwd<512>(zr, zi, tid);
  const float bo = bias[row];
  const float s = 1.0f / (float)NFFT;  // folds the 1/N of the inverse transform
  __hip_bfloat162* out2 = (__hip_bfloat162*)h;
  for (int p = tid; p < NFFT; p += 512) {
    __hip_bfloat162 w;
    w.x = __float2bfloat16((zr[p] + bo) * s);
    w.y = __float2bfloat16(zi[p] * s);
    out2[p] = w;
  }
}

// ===========================================================================
// Kernel G1: in_proj GEMM, fp32. C = u @ W + b, written TRANSPOSED:
// up_t[(b*2304 + n)*8192 + t]  (FFT rows contiguous in t)
// ===========================================================================
__global__ __launch_bounds__(256)
void inproj_gemm_kernel(const float* __restrict__ A, const float* __restrict__ Bw,
                        const float* __restrict__ bias, float* __restrict__ up_t)
{
  __shared__ __align__(16) float As[16][64];
  __shared__ __align__(16) float Bs[16][64];
  const int tid = threadIdx.x;
  const int tx = tid & 15, ty = tid >> 4;
  const int m0 = blockIdx.y * 64, n0 = blockIdx.x * 64;
  const int arow = tid >> 2, acol = (tid & 3) << 2;
  const int brow = tid >> 4, bcol = (tid & 15) << 2;

  float acc[4][4] = {{0.0f}};
  for (int k0 = 0; k0 < D_DIM; k0 += 16) {
    float4 av = *(const float4*)&A[(size_t)(m0 + arow) * D_DIM + k0 + acol];
    float4 bv = *(const float4*)&Bw[(size_t)(k0 + brow) * C_IN + n0 + bcol];
    As[acol + 0][arow] = av.x;
    As[acol + 1][arow] = av.y;
    As[acol + 2][arow] = av.z;
    As[acol + 3][arow] = av.w;
    *(float4*)&Bs[brow][bcol] = bv;
    __syncthreads();
    #pragma unroll
    for (int kk = 0; kk < 16; ++kk) {
      const float4 a = *(const float4*)&As[kk][ty << 2];
      const float4 b = *(const float4*)&Bs[kk][tx << 2];
      acc[0][0] += a.x*b.x; acc[0][1] += a.x*b.y; acc[0][2] += a.x*b.z; acc[0][3] += a.x*b.w;
      acc[1][0] += a.y*b.x; acc[1][1] += a.y*b.y; acc[1][2] += a.y*b.z; acc[1][3] += a.y*b.w;
      acc[2][0] += a.z*b.x; acc[2][1] += a.z*b.y; acc[2][2] += a.z*b.z; acc[2][3] += a.z*b.w;
      acc[3][0] += a.w*b.x; acc[3][1] += a.w*b.y; acc[3][2] += a.w*b.z; acc[3][3] += a.w*b.w;
    }
    __syncthreads();
  }
  const int bidx = m0 >> 13;
  const int t0 = (m0 & (L_SEQ - 1)) + (ty << 2);
  const float4 bo = *(const float4*)&bias[n0 + (tx << 2)];
  const float bja[4] = {bo.x, bo.y, bo.z, bo.w};
  #pragma unroll
  for (int j = 0; j < 4; ++j) {
    const int n = n0 + (tx << 2) + j;
    float4 w;
    w.x = acc[0][j] + bja[j];
    w.y = acc[1][j] + bja[j];
    w.z = acc[2][j] + bja[j];
    w.w = acc[3][j] + bja[j];
    *(float4*)&up_t[((size_t)bidx * C_IN + n) * L_SEQ + t0] = w;
  }
}

// ===========================================================================
// Kernel C: fused shortconv + 2x (FFT conv + gate). One block per channel f.
// Batch-pairing: z = v_b0 + i*v_b1 ; real filter => conv acts componentwise.
// Output v rows are written into this block's own CONSUMED spectrum row
// (row f of hH), so no extra workspace region:
//   v[b][f][t]  at float offset  f*16384 + b*8192 + t
// ===========================================================================
__global__ __launch_bounds__(512)
void fftconv_kernel(const float* __restrict__ up, float* __restrict__ hH,
                    const float* __restrict__ sw, const float* __restrict__ sb)
{
  __shared__ float zr[NFFT];
  __shared__ float zi[NFFT];
  const int f = blockIdx.x;
  const int tid = threadIdx.x;

  { // pack v = shortconv(up[:, f, :]) for both batches; zero-pad top half
    const float* u0 = up + (size_t)(0 * C_IN + f) * L_SEQ;
    const float* u1 = up + (size_t)(1 * C_IN + f) * L_SEQ;
    const float vw0 = sw[f], vw1 = sw[C_IN + f], vw2 = sw[2 * C_IN + f];
    const float vb = sb[f];
    for (int t = tid; t < L_SEQ; t += 512) {
      zr[t] = conv3(u0, t, vw0, vw1, vw2, vb);
      zi[t] = conv3(u1, t, vw0, vw1, vw2, vb);
    }
    for (int t = L_SEQ + tid; t < NFFT; t += 512) { zr[t] = 0.0f; zi[t] = 0.0f; }
  }
  __syncthreads();

  for (int o = 0; o < NORD; ++o) {
    fft4_fwd<512>(zr, zi, tid);
    { // pointwise spectrum multiply (bf16 H, permuted order matches)
      const __hip_bfloat162* H =
          (const __hip_bfloat162*)(hH + (size_t)(o * F_DIM + f) * NFFT);
      for (int p = tid; p < NFFT; p += 512) {
        const __hip_bfloat162 h2 = H[p];
        const float hr = __bfloat162float(h2.x), hi = __bfloat162float(h2.y);
        const float ar = zr[p], ai = zi[p];
        zr[p] = ar * hr - ai * hi;
        zi[p] = ar * hi + ai * hr;
      }
    }
    __syncthreads();
    fft4_inv<512>(zr, zi, tid);

    // gate with x_o = shortconv(up[:, (o+1)*768+f, :]); repack or store
    const int c = (o + 1) * F_DIM + f;
    const float* x0 = up + (size_t)(0 * C_IN + c) * L_SEQ;
    const float* x1 = up + (size_t)(1 * C_IN + c) * L_SEQ;
    const float xw0 = sw[c], xw1 = sw[C_IN + c], xw2 = sw[2 * C_IN + c];
    const float xb = sb[c];
    if (o == 0) {
      for (int t = tid; t < L_SEQ; t += 512) {
        zr[t] *= conv3(x0, t, xw0, xw1, xw2, xb);
        zi[t] *= conv3(x1, t, xw0, xw1, xw2, xb);
      }
      for (int t = L_SEQ + tid; t < NFFT; t += 512) { zr[t] = 0.0f; zi[t] = 0.0f; }
      __syncthreads();
    } else {
      float* v0 = hH + (size_t)f * NFFT;          // row f already consumed (o=0)
      float* v1 = v0 + L_SEQ;
      for (int t = tid; t < L_SEQ; t += 512) {
        v0[t] = zr[t] * conv3(x0, t, xw0, xw1, xw2, xb);
        v1[t] = zi[t] * conv3(x1, t, xw0, xw1, xw2, xb);
      }
    }
  }
}

// ===========================================================================
// Kernel G2: out GEMM, fp32. A rows live at hH + k*16384 + b*8192 + t
// (k = filter channel f). out[(b*8192+t)*768 + d].
// ===========================================================================
__global__ __launch_bounds__(256)
void out_gemm_kernel(const float* __restrict__ vt, const float* __restrict__ Bw,
                     const float* __restrict__ bias, float* __restrict__ out)
{
  __shared__ __align__(16) float As[16][64];
  __shared__ __align__(16) float Bs[16][64];
  const int tid = threadIdx.x;
  const int tx = tid & 15, ty = tid >> 4;
  const int m0 = blockIdx.y * 64, n0 = blockIdx.x * 64;
  const int bidx = m0 >> 13;
  const int t0 = m0 & (L_SEQ - 1);
  const int arow = tid >> 4, acol = (tid & 15) << 2;
  const int brow = tid >> 4, bcol = (tid & 15) << 2;

  float acc[4][4] = {{0.0f}};
  for (int k0 = 0; k0 < F_DIM; k0 += 16) {
    float4 av = *(const float4*)&vt[(size_t)(k0 + arow) * NFFT + (size_t)bidx * L_SEQ + t0 + acol];
    float4 bv = *(const float4*)&Bw[(size_t)(k0 + brow) * D_DIM + n0 + bcol];
    *(float4*)&As[arow][acol] = av;
    *(float4*)&Bs[brow][bcol] = bv;
    __syncthreads();
    #pragma unroll
    for (int kk = 0; kk < 16; ++kk) {
      const float4 a = *(const float4*)&As[kk][ty << 2];
      const float4 b = *(const float4*)&Bs[kk][tx << 2];
      acc[0][0] += a.x*b.x; acc[0][1] += a.x*b.y; acc[0][2] += a.x*b.z; acc[0][3] += a.x*b.w;
      acc[1][0] += a.y*b.x; acc[1][1] += a.y*b.y; acc[1][2] += a.y*b.z; acc[1][3] += a.y*b.w;
      acc[2][0] += a.z*b.x; acc[2][1] += a.z*b.y; acc[2][2] += a.z*b.z; acc[2][3] += a.z*b.w;
      acc[3][0] += a.w*b.x; acc[3][1] += a.w*b.y; acc[3][2] += a.w*b.z; acc[3][3] += a.w*b.w;
    }
    __syncthreads();
  }
  const float4 bo = *(const float4*)&bias[n0 + (tx << 2)];
  #pragma unroll
  for (int i = 0; i < 4; ++i) {
    const int m = m0 + (ty << 2) + i;
    float4 w;
    w.x = acc[i][0] + bo.x;
    w.y = acc[i][1] + bo.y;
    w.z = acc[i][2] + bo.z;
    w.w = acc[i][3] + bo.w;
    *(float4*)&out[(size_t)m * D_DIM + n0 + (tx << 2)] = w;
  }
}

// ===========================================================================
extern "C" void kernel_launch(void* const* d_in, const int* in_sizes, int n_in,
                              void* d_out, int out_size, void* d_ws, size_t ws_size,
                              hipStream_t stream)
{
  (void)in_sizes; (void)n_in; (void)out_size; (void)ws_size;
  const float* u     = (const float*)d_in[0];
  const float* fw1   = (const float*)d_in[1];
  const float* fb1   = (const float*)d_in[2];
  const float* fw2   = (const float*)d_in[3];
  const float* fb2   = (const float*)d_in[4];
  const float* decay = (const float*)d_in[5];
  const float* bias  = (const float*)d_in[6];
  const float* ipw   = (const float*)d_in[7];
  const float* ipb   = (const float*)d_in[8];
  const float* sw    = (const float*)d_in[9];
  const float* sb    = (const float*)d_in[10];
  const float* ow    = (const float*)d_in[11];
  const float* ob    = (const float*)d_in[12];
  float* out = (float*)d_out;

  // Workspace (floats): up_t 37,748,736 + hH 25,165,824 = 62,914,560 floats
  // = 251,658,240 bytes (240 MiB). hH holds, in sequence: h (fp32 rows) ->
  // H spectra (bf16x2, in place) -> v outputs (fp32, in consumed rows).
  float* ws   = (float*)d_ws;
  float* up_t = ws;
  float* hH   = up_t + (size_t)2 * C_IN * L_SEQ;

  filter_gen_kernel<<<dim3(NFFT / 64, 1536 / 256), 256, 0, stream>>>(fw1, fb1, fw2, fb2, decay, hH);
  filter_fft_kernel<<<dim3(NORD * F_DIM), 512, 0, stream>>>(hH, bias);
  inproj_gemm_kernel<<<dim3(C_IN / 64, (2 * L_SEQ) / 64), 256, 0, stream>>>(u, ipw, ipb, up_t);
  fftconv_kernel<<<dim3(F_DIM), 512, 0, stream>>>(up_t, hH, sw, sb);
  out_gemm_kernel<<<dim3(D_DIM / 64, (2 * L_SEQ) / 64), 256, 0, stream>>>(hH, ow, ob, out);
}

// Round 3
// 984.304 us; speedup vs baseline: 1.8222x; 1.8222x over previous
//
#include <hip/hip_runtime.h>
#include <hip/hip_bf16.h>
#include <math.h>

#define L_SEQ 8192
#define NFFT  16384
#define F_DIM 768
#define D_DIM 768
#define C_IN  2304   // INNER = F*(ORDER+1)
#define NORD  2

typedef unsigned short u16;
typedef __attribute__((ext_vector_type(8))) short bf16x8;
typedef __attribute__((ext_vector_type(4))) float f32x4;
struct __align__(8) U16x4 { u16 x, y, z, w; };

__device__ __forceinline__ float bf2f(u16 v) {
  unsigned u = ((unsigned)v) << 16; float f; __builtin_memcpy(&f, &u, 4); return f;
}
__device__ __forceinline__ u16 f2bf(float f) {
  __hip_bfloat16 h = __float2bfloat16(f); u16 r; __builtin_memcpy(&r, &h, 2); return r;
}

// ===========================================================================
// Radix-4 FFT over LDS, N = 16384 = 4^7 (fwd DIF nat->rev, inv DIT rev->nat,
// inverse unnormalized). Same routines as round 2 (verified).
// ===========================================================================
template<int NT>
__device__ __forceinline__ void fft4_fwd(float* zr, float* zi, int tid)
{
  for (int lq = 12; lq >= 0; lq -= 2) {
    const int q = 1 << lq;
    const float stw = -6.2831853071795864769f / (float)(q << 2);
    for (int b = tid; b < NFFT / 4; b += NT) {
      const int j = b & (q - 1);
      const int base = ((b >> lq) << (lq + 2)) + j;
      float a0r = zr[base        ], a0i = zi[base        ];
      float a1r = zr[base +     q], a1i = zi[base +     q];
      float a2r = zr[base + 2 * q], a2i = zi[base + 2 * q];
      float a3r = zr[base + 3 * q], a3i = zi[base + 3 * q];
      float t0r = a0r + a2r, t0i = a0i + a2i;
      float t1r = a0r - a2r, t1i = a0i - a2i;
      float t2r = a1r + a3r, t2i = a1i + a3i;
      float t3r = a1r - a3r, t3i = a1i - a3i;
      float y0r = t0r + t2r, y0i = t0i + t2i;
      float y1r = t1r + t3i, y1i = t1i - t3r;
      float y2r = t0r - t2r, y2i = t0i - t2i;
      float y3r = t1r - t3i, y3i = t1i + t3r;
      float ang = stw * (float)j;
      float s1, c1; __sincosf(ang, &s1, &c1);
      float c2 = c1 * c1 - s1 * s1, s2 = 2.0f * c1 * s1;
      float c3 = c1 * c2 - s1 * s2, s3 = c1 * s2 + s1 * c2;
      zr[base        ] = y0r;
      zi[base        ] = y0i;
      zr[base +     q] = y1r * c1 - y1i * s1;
      zi[base +     q] = y1r * s1 + y1i * c1;
      zr[base + 2 * q] = y2r * c2 - y2i * s2;
      zi[base + 2 * q] = y2r * s2 + y2i * c2;
      zr[base + 3 * q] = y3r * c3 - y3i * s3;
      zi[base + 3 * q] = y3r * s3 + y3i * c3;
    }
    __syncthreads();
  }
}

template<int NT>
__device__ __forceinline__ void fft4_inv(float* zr, float* zi, int tid)
{
  for (int lq = 0; lq <= 12; lq += 2) {
    const int q = 1 << lq;
    const float stw = 6.2831853071795864769f / (float)(q << 2);
    for (int b = tid; b < NFFT / 4; b += NT) {
      const int j = b & (q - 1);
      const int base = ((b >> lq) << (lq + 2)) + j;
      float u0r = zr[base        ], u0i = zi[base        ];
      float z1r = zr[base +     q], z1i = zi[base +     q];
      float z2r = zr[base + 2 * q], z2i = zi[base + 2 * q];
      float z3r = zr[base + 3 * q], z3i = zi[base + 3 * q];
      float ang = stw * (float)j;
      float s1, c1; __sincosf(ang, &s1, &c1);
      float c2 = c1 * c1 - s1 * s1, s2 = 2.0f * c1 * s1;
      float c3 = c1 * c2 - s1 * s2, s3 = c1 * s2 + s1 * c2;
      float u1r = z1r * c1 - z1i * s1, u1i = z1r * s1 + z1i * c1;
      float u2r = z2r * c2 - z2i * s2, u2i = z2r * s2 + z2i * c2;
      float u3r = z3r * c3 - z3i * s3, u3i = z3r * s3 + z3i * c3;
      float e0r = u0r + u2r, e0i = u0i + u2i;
      float e1r = u0r - u2r, e1i = u0i - u2i;
      float f0r = u1r + u3r, f0i = u1i + u3i;
      float f1r = u1r - u3r, f1i = u1i - u3i;
      zr[base        ] = e0r + f0r; zi[base        ] = e0i + f0i;
      zr[base +     q] = e1r - f1i; zi[base +     q] = e1i + f1r;
      zr[base + 2 * q] = e0r - f0r; zi[base + 2 * q] = e0i - f0i;
      zr[base + 3 * q] = e1r + f1i; zi[base + 3 * q] = e1i - f1r;
    }
    __syncthreads();
  }
}

// depthwise conv3 on a bf16 row, SAME padding (XLA cross-correlation)
__device__ __forceinline__ float conv3b(const u16* __restrict__ row, int t,
                                        float w0, float w1, float w2, float sb)
{
  float l = (t > 0)         ? bf2f(row[t - 1]) : 0.0f;
  float c = bf2f(row[t]);
  float r = (t < L_SEQ - 1) ? bf2f(row[t + 1]) : 0.0f;
  return w0 * l + w1 * c + w2 * r + sb;
}

// ===========================================================================
// Prep kernels: fp32->bf16 cast (row-major) and transpose-cast [K][N]->[N][K]
// ===========================================================================
__global__ __launch_bounds__(256)
void cast_bf16_kernel(const float* __restrict__ in, u16* __restrict__ out, int n4)
{
  int i = blockIdx.x * 256 + threadIdx.x;
  if (i < n4) {
    float4 v = ((const float4*)in)[i];
    U16x4 w; w.x = f2bf(v.x); w.y = f2bf(v.y); w.z = f2bf(v.z); w.w = f2bf(v.w);
    ((U16x4*)out)[i] = w;
  }
}

__global__ __launch_bounds__(256)
void transpose_cast_kernel(const float* __restrict__ in, u16* __restrict__ out,
                           int K, int N)   // in [K][N] fp32 -> out [N][K] bf16
{
  __shared__ u16 tile[32][33];
  const int n0 = blockIdx.x * 32, k0 = blockIdx.y * 32;
  const int tx = threadIdx.x & 31, ty = threadIdx.x >> 5;  // ty in [0,8)
  #pragma unroll
  for (int i = 0; i < 32; i += 8)
    tile[ty + i][tx] = f2bf(in[(size_t)(k0 + ty + i) * N + n0 + tx]);
  __syncthreads();
  #pragma unroll
  for (int i = 0; i < 32; i += 8)
    out[(size_t)(n0 + ty + i) * K + k0 + tx] = tile[tx][ty + i];
}

// v bf16 rows (row f at u16-offset f*2*NFFT, length 16384=m) -> vt_t [m][768]
__global__ __launch_bounds__(256)
void transpose_v_kernel(const u16* __restrict__ vb, u16* __restrict__ out)
{
  __shared__ u16 t2[64][65];
  const int m0 = blockIdx.x * 64, f0 = blockIdx.y * 64;
  const int tx = threadIdx.x & 63, ty = threadIdx.x >> 6;  // ty in [0,4)
  #pragma unroll
  for (int i = 0; i < 64; i += 4)
    t2[ty + i][tx] = vb[(size_t)(f0 + ty + i) * (2 * NFFT) + m0 + tx];
  __syncthreads();
  #pragma unroll
  for (int i = 0; i < 64; i += 4)
    out[(size_t)(m0 + ty + i) * F_DIM + f0 + tx] = t2[tx][ty + i];
}

// ===========================================================================
// MFMA GEMM (m97 pattern): C[M][N] = A[M][K] @ B[N][K]^T + bias.
// 128x128 tile, BK=64, 256 thr (4 waves, 2x2 of 64x64), 16x16x32 bf16 MFMA,
// width-16 global_load_lds staging. WMODE 0: write up_t bf16 transposed
// [(b*N+n)*8192 + t]; WMODE 1: write fp32 natural [m*N + n].
// ===========================================================================
template<int N_DIM, int K_DIM, int WMODE>
__global__ __launch_bounds__(256)
void mfma_gemm_kernel(const u16* __restrict__ A, const u16* __restrict__ B,
                      const float* __restrict__ bias, void* __restrict__ Cv)
{
  constexpr int BK = 64;
  __shared__ u16 As[128 * BK];   // [m][k], 16 KB
  __shared__ u16 Bs[128 * BK];   // [n][k], 16 KB
  const int tid  = threadIdx.x;
  const int lane = tid & 63;
  const int wid  = tid >> 6;
  const int m0 = blockIdx.x * 128;
  const int n0 = blockIdx.y * 128;

  // staging pointers: granule g (16B) <-> (row=g>>3, kchunk=g&7)
  const u16* aPtr[4]; const u16* bPtr[4];
  #pragma unroll
  for (int i = 0; i < 4; ++i) {
    const int g = tid + (i << 8);
    aPtr[i] = A + (size_t)(m0 + (g >> 3)) * K_DIM + ((g & 7) << 3);
    bPtr[i] = B + (size_t)(n0 + (g >> 3)) * K_DIM + ((g & 7) << 3);
  }

  const int wm = (wid & 1) << 6;   // wave m-offset in tile
  const int wn = (wid >> 1) << 6;  // wave n-offset in tile
  int aoff[4], boff[4];
  #pragma unroll
  for (int f = 0; f < 4; ++f) {
    aoff[f] = (wm + f * 16 + (lane & 15)) * BK + ((lane >> 4) << 3);
    boff[f] = (wn + f * 16 + (lane & 15)) * BK + ((lane >> 4) << 3);
  }

  f32x4 acc[4][4];
  #pragma unroll
  for (int i = 0; i < 4; ++i)
    #pragma unroll
    for (int j = 0; j < 4; ++j)
      acc[i][j] = (f32x4){0.f, 0.f, 0.f, 0.f};

  for (int k0 = 0; k0 < K_DIM; k0 += BK) {
    #pragma unroll
    for (int i = 0; i < 4; ++i) {
      __builtin_amdgcn_global_load_lds(
          (const __attribute__((address_space(1))) void*)aPtr[i],
          (__attribute__((address_space(3))) void*)&As[(((wid << 6) + (i << 8)) << 3)],
          16, 0, 0);
      aPtr[i] += BK;
    }
    #pragma unroll
    for (int i = 0; i < 4; ++i) {
      __builtin_amdgcn_global_load_lds(
          (const __attribute__((address_space(1))) void*)bPtr[i],
          (__attribute__((address_space(3))) void*)&Bs[(((wid << 6) + (i << 8)) << 3)],
          16, 0, 0);
      bPtr[i] += BK;
    }
    __syncthreads();
    #pragma unroll
    for (int kk = 0; kk < 2; ++kk) {
      bf16x8 af[4], bg[4];
      #pragma unroll
      for (int f = 0; f < 4; ++f) af[f] = *(const bf16x8*)&As[aoff[f] + kk * 32];
      #pragma unroll
      for (int f = 0; f < 4; ++f) bg[f] = *(const bf16x8*)&Bs[boff[f] + kk * 32];
      #pragma unroll
      for (int fm = 0; fm < 4; ++fm)
        #pragma unroll
        for (int fn = 0; fn < 4; ++fn)
          acc[fm][fn] = __builtin_amdgcn_mfma_f32_16x16x32_bf16(
              af[fm], bg[fn], acc[fm][fn], 0, 0, 0);
    }
    __syncthreads();
  }

  // C-frag: n = 16*fn + (lane&15), m = 16*fm + (lane>>4)*4 + reg  [m89-verified]
  if (WMODE == 0) {
    u16* C = (u16*)Cv;
    const int b = m0 >> 13;
    const int tbase = (m0 & (L_SEQ - 1)) + wm + ((lane >> 4) << 2);
    #pragma unroll
    for (int fn = 0; fn < 4; ++fn) {
      const int n = n0 + wn + fn * 16 + (lane & 15);
      const float bv = bias[n];
      u16* row = C + ((size_t)b * N_DIM + n) * L_SEQ;
      #pragma unroll
      for (int fm = 0; fm < 4; ++fm) {
        f32x4 v = acc[fm][fn];
        U16x4 w;
        w.x = f2bf(v[0] + bv); w.y = f2bf(v[1] + bv);
        w.z = f2bf(v[2] + bv); w.w = f2bf(v[3] + bv);
        *(U16x4*)&row[tbase + fm * 16] = w;
      }
    }
  } else {
    float* C = (float*)Cv;
    #pragma unroll
    for (int fn = 0; fn < 4; ++fn) {
      const int n = n0 + wn + fn * 16 + (lane & 15);
      const float bv = bias[n];
      #pragma unroll
      for (int fm = 0; fm < 4; ++fm) {
        const int mb = m0 + wm + fm * 16 + ((lane >> 4) << 2);
        f32x4 v = acc[fm][fn];
        #pragma unroll
        for (int r = 0; r < 4; ++r)
          C[(size_t)(mb + r) * N_DIM + n] = v[r] + bv;
      }
    }
  }
}

// ===========================================================================
// Kernel A: filter MLP -> h[(o*768+f)][tau] fp32 (unchanged, verified)
// ===========================================================================
__global__ __launch_bounds__(256)
void filter_gen_kernel(const float* __restrict__ w1, const float* __restrict__ b1,
                       const float* __restrict__ w2, const float* __restrict__ b2,
                       const float* __restrict__ decay, float* __restrict__ h_t)
{
  __shared__ float hid[64][65];
  const int tid  = threadIdx.x;
  const int tau0 = blockIdx.x * 64;
  const int c0   = blockIdx.y * 256;
  {
    const int r = tid & 63;
    const int tb = tid >> 6;
    const float w1v0 = w1[r];
    const float b1v = b1[r];
    float w1c[4], w1s[4];
    #pragma unroll
    for (int p = 0; p < 4; ++p) { w1c[p] = w1[(1 + p) * 64 + r]; w1s[p] = w1[(5 + p) * 64 + r]; }
    #pragma unroll
    for (int i = 0; i < 16; ++i) {
      const int tl = tb + i * 4;
      const int tau = tau0 + tl;
      const float off = (tau < L_SEQ) ? (float)tau : (float)(tau - NFFT);
      float acc = b1v + off * (1.0f / 8192.0f) * w1v0;
      #pragma unroll
      for (int p = 0; p < 4; ++p) {
        const double period = 4.0 + (8188.0 * p) / 3.0;
        const float freq = (float)(6.283185307179586476925287 / period);
        float sp, cp;
        sincosf(off * freq, &sp, &cp);
        acc += cp * w1c[p] + sp * w1s[p];
      }
      hid[r][tl] = sinf(acc);
    }
  }
  __syncthreads();

  const int tx = tid & 63;
  const int ty = tid >> 6;
  const int taug = tau0 + tx;
  const float mt = (taug < L_SEQ) ? (float)taug * (1.0f / 8191.0f)
                                  : (float)(NFFT - 1 - taug) * (1.0f / 8191.0f);
  const int cbase = c0 + ty * 64;
  for (int cb = 0; cb < 8; ++cb) {
    const int c8 = cbase + cb * 8;
    float acc[8];
    #pragma unroll
    for (int jj = 0; jj < 8; ++jj) acc[jj] = b2[c8 + jj];
    for (int rr = 0; rr < 64; ++rr) {
      const float hv = hid[rr][tx];
      const float4 wa = *(const float4*)&w2[rr * 1536 + c8];
      const float4 wb = *(const float4*)&w2[rr * 1536 + c8 + 4];
      acc[0] += hv * wa.x; acc[1] += hv * wa.y; acc[2] += hv * wa.z; acc[3] += hv * wa.w;
      acc[4] += hv * wb.x; acc[5] += hv * wb.y; acc[6] += hv * wb.z; acc[7] += hv * wb.w;
    }
    #pragma unroll
    for (int jj = 0; jj < 8; ++jj) {
      const int c = c8 + jj;
      const float dec = __expf(-mt * fabsf(decay[c]));
      h_t[(size_t)c * NFFT + taug] = acc[jj] * dec;
    }
  }
}

// ===========================================================================
// Kernel B: filter spectra IN PLACE (fp32 row -> bf16x2 spectrum; bias folded)
// ===========================================================================
__global__ __launch_bounds__(512)
void filter_fft_kernel(float* __restrict__ hH, const float* __restrict__ bias)
{
  __shared__ float zr[NFFT];
  __shared__ float zi[NFFT];
  const int row = blockIdx.x;
  const int tid = threadIdx.x;
  float* h = hH + (size_t)row * NFFT;
  for (int t = tid; t < NFFT; t += 512) { zr[t] = h[t]; zi[t] = 0.0f; }
  __syncthreads();
  fft4_fwd<512>(zr, zi, tid);
  const float bo = bias[row];
  const float s = 1.0f / (float)NFFT;
  __hip_bfloat162* out2 = (__hip_bfloat162*)h;
  for (int p = tid; p < NFFT; p += 512) {
    __hip_bfloat162 w;
    w.x = __float2bfloat16((zr[p] + bo) * s);
    w.y = __float2bfloat16(zi[p] * s);
    out2[p] = w;
  }
}

// ===========================================================================
// Kernel C: fused shortconv + 2x (FFT conv + gate); up is bf16 now; v rows
// written bf16 into this block's consumed H row f (b0 at [0,8192), b1 next).
// ===========================================================================
__global__ __launch_bounds__(512)
void fftconv_kernel(const u16* __restrict__ up, float* __restrict__ hH,
                    const float* __restrict__ sw, const float* __restrict__ sb)
{
  __shared__ float zr[NFFT];
  __shared__ float zi[NFFT];
  const int f = blockIdx.x;
  const int tid = threadIdx.x;

  {
    const u16* u0 = up + (size_t)(0 * C_IN + f) * L_SEQ;
    const u16* u1 = up + (size_t)(1 * C_IN + f) * L_SEQ;
    const float vw0 = sw[f], vw1 = sw[C_IN + f], vw2 = sw[2 * C_IN + f];
    const float vb = sb[f];
    for (int t = tid; t < L_SEQ; t += 512) {
      zr[t] = conv3b(u0, t, vw0, vw1, vw2, vb);
      zi[t] = conv3b(u1, t, vw0, vw1, vw2, vb);
    }
    for (int t = L_SEQ + tid; t < NFFT; t += 512) { zr[t] = 0.0f; zi[t] = 0.0f; }
  }
  __syncthreads();

  for (int o = 0; o < NORD; ++o) {
    fft4_fwd<512>(zr, zi, tid);
    {
      const __hip_bfloat162* H =
          (const __hip_bfloat162*)(hH + (size_t)(o * F_DIM + f) * NFFT);
      for (int p = tid; p < NFFT; p += 512) {
        const __hip_bfloat162 h2 = H[p];
        const float hr = __bfloat162float(h2.x), hi = __bfloat162float(h2.y);
        const float ar = zr[p], ai = zi[p];
        zr[p] = ar * hr - ai * hi;
        zi[p] = ar * hi + ai * hr;
      }
    }
    __syncthreads();
    fft4_inv<512>(zr, zi, tid);

    const int c = (o + 1) * F_DIM + f;
    const u16* x0 = up + (size_t)(0 * C_IN + c) * L_SEQ;
    const u16* x1 = up + (size_t)(1 * C_IN + c) * L_SEQ;
    const float xw0 = sw[c], xw1 = sw[C_IN + c], xw2 = sw[2 * C_IN + c];
    const float xb = sb[c];
    if (o == 0) {
      for (int t = tid; t < L_SEQ; t += 512) {
        zr[t] *= conv3b(x0, t, xw0, xw1, xw2, xb);
        zi[t] *= conv3b(x1, t, xw0, xw1, xw2, xb);
      }
      for (int t = L_SEQ + tid; t < NFFT; t += 512) { zr[t] = 0.0f; zi[t] = 0.0f; }
      __syncthreads();
    } else {
      u16* v01 = (u16*)(hH + (size_t)f * NFFT);   // row f consumed at o=0
      for (int t = tid; t < L_SEQ; t += 512) {
        v01[t]         = f2bf(zr[t] * conv3b(x0, t, xw0, xw1, xw2, xb));
        v01[L_SEQ + t] = f2bf(zi[t] * conv3b(x1, t, xw0, xw1, xw2, xb));
      }
    }
  }
}

// ===========================================================================
extern "C" void kernel_launch(void* const* d_in, const int* in_sizes, int n_in,
                              void* d_out, int out_size, void* d_ws, size_t ws_size,
                              hipStream_t stream)
{
  (void)in_sizes; (void)n_in; (void)out_size; (void)ws_size;
  const float* u     = (const float*)d_in[0];
  const float* fw1   = (const float*)d_in[1];
  const float* fb1   = (const float*)d_in[2];
  const float* fw2   = (const float*)d_in[3];
  const float* fb2   = (const float*)d_in[4];
  const float* decay = (const float*)d_in[5];
  const float* bias  = (const float*)d_in[6];
  const float* ipw   = (const float*)d_in[7];
  const float* ipb   = (const float*)d_in[8];
  const float* sw    = (const float*)d_in[9];
  const float* sb    = (const float*)d_in[10];
  const float* ow    = (const float*)d_in[11];
  const float* ob    = (const float*)d_in[12];
  float* out = (float*)d_out;

  // Workspace layout (bytes), total 231,211,008 < 240 MiB known-good:
  char* ws = (char*)d_ws;
  u16*   up_t  = (u16*)(ws);                                // [b*2304+n][8192] bf16, 75,497,472 B
  float* hH    = (float*)(ws + 75497472);                   // 1536*16384 fp32, 100,663,296 B
  u16*   u_bf  = (u16*)(ws + 176160768);                    // [m][768] bf16, 25,165,824 B
  u16*   ipw_t = (u16*)(ws + 201326592);                    // [2304][768] bf16, 3,538,944 B
  u16*   ow_t  = (u16*)(ws + 204865536);                    // [768][768] bf16, 1,179,648 B
  u16*   vt_t  = (u16*)(ws + 206045184);                    // [m][768] bf16, 25,165,824 B

  cast_bf16_kernel<<<dim3(12288), 256, 0, stream>>>(u, u_bf, (2 * L_SEQ * D_DIM) / 4);
  transpose_cast_kernel<<<dim3(C_IN / 32, D_DIM / 32), 256, 0, stream>>>(ipw, ipw_t, D_DIM, C_IN);
  transpose_cast_kernel<<<dim3(D_DIM / 32, F_DIM / 32), 256, 0, stream>>>(ow, ow_t, F_DIM, D_DIM);

  filter_gen_kernel<<<dim3(NFFT / 64, 1536 / 256), 256, 0, stream>>>(fw1, fb1, fw2, fb2, decay, hH);
  filter_fft_kernel<<<dim3(NORD * F_DIM), 512, 0, stream>>>(hH, bias);

  mfma_gemm_kernel<C_IN, D_DIM, 0><<<dim3(128, C_IN / 128), 256, 0, stream>>>(u_bf, ipw_t, ipb, up_t);
  fftconv_kernel<<<dim3(F_DIM), 512, 0, stream>>>(up_t, hH, sw, sb);
  transpose_v_kernel<<<dim3(NFFT / 64, F_DIM / 64), 256, 0, stream>>>((const u16*)hH, vt_t);
  mfma_gemm_kernel<D_DIM, F_DIM, 1><<<dim3(128, D_DIM / 128), 256, 0, stream>>>(vt_t, ow_t, ob, out);
}

// Round 4
// 843.357 us; speedup vs baseline: 2.1267x; 1.1671x over previous
//
#include <hip/hip_runtime.h>
#include <hip/hip_bf16.h>
#include <math.h>

#define L_SEQ 8192
#define NFFT  16384
#define NPAD  16896   // NFFT + NFFT/32 padding
#define F_DIM 768
#define D_DIM 768
#define C_IN  2304   // INNER = F*(ORDER+1)
#define NORD  2

typedef unsigned short u16;
typedef __attribute__((ext_vector_type(8))) short bf16x8;
typedef __attribute__((ext_vector_type(4))) float f32x4;
struct __align__(8) U16x4 { u16 x, y, z, w; };

__device__ __forceinline__ float bf2f(u16 v) {
  unsigned u = ((unsigned)v) << 16; float f; __builtin_memcpy(&f, &u, 4); return f;
}
__device__ __forceinline__ u16 f2bf(float f) {
  __hip_bfloat16 h = __float2bfloat16(f); u16 r; __builtin_memcpy(&r, &h, 2); return r;
}

// LDS pad: bank(i) shifts by 1 every 32 floats -> all FFT strides <=2-way (free)
__device__ __forceinline__ int PAD(int i) { return i + (i >> 5); }

__device__ __forceinline__ void rot3(float ang, float& c1, float& s1,
                                     float& c2, float& s2, float& c3, float& s3)
{
  __sincosf(ang, &s1, &c1);
  c2 = c1 * c1 - s1 * s1; s2 = 2.0f * c1 * s1;
  c3 = c1 * c2 - s1 * s2; s3 = c1 * s2 + s1 * c2;
}

// ===========================================================================
// Radix-4 FFT over padded LDS, N = 16384 = 4^7, stage pairs fused in regs.
// fwd: DIF stages (12,10)(8,6)(4,2)(0), natural -> digit-reversed.
// inv: DIT stages (0)(2,4)(6,8)(10,12), digit-reversed -> natural, UNNORM.
// Identical stage algebra & in-place positions as the verified r2/r3 version;
// only the staging through registers and the LDS pad mapping changed.
// ===========================================================================
template<int NT>
__device__ __forceinline__ void fft4_fwd(float* zr, float* zi, int tid)
{
  #pragma unroll
  for (int lq = 12; lq >= 4; lq -= 4) {      // fused pair: stage lq then lq-2
    const int q  = 1 << lq;
    const int q4 = q >> 2;
    const float stw1 = -6.2831853071795864769f / (float)(q << 2);  // 2pi/(4q)
    const float stw2 = -6.2831853071795864769f / (float)q;         // 2pi/(4*q4)
    for (int g = tid; g < NFFT / 16; g += NT) {
      const int j    = g & (q4 - 1);
      const int base = ((g >> (lq - 2)) << (lq + 2)) + j;
      float xr[4][4], xi4[4][4];             // [k][m]: pos = base + m*q4 + k*q
      #pragma unroll
      for (int k = 0; k < 4; ++k)
        #pragma unroll
        for (int m = 0; m < 4; ++m) {
          const int idx = PAD(base + m * q4 + k * q);
          xr[k][m] = zr[idx]; xi4[k][m] = zi[idx];
        }
      #pragma unroll
      for (int m = 0; m < 4; ++m) {          // layer 1: stage lq, j1 = j+m*q4
        float t0r = xr[0][m] + xr[2][m], t0i = xi4[0][m] + xi4[2][m];
        float t1r = xr[0][m] - xr[2][m], t1i = xi4[0][m] - xi4[2][m];
        float t2r = xr[1][m] + xr[3][m], t2i = xi4[1][m] + xi4[3][m];
        float t3r = xr[1][m] - xr[3][m], t3i = xi4[1][m] - xi4[3][m];
        float y0r = t0r + t2r, y0i = t0i + t2i;
        float y1r = t1r + t3i, y1i = t1i - t3r;
        float y2r = t0r - t2r, y2i = t0i - t2i;
        float y3r = t1r - t3i, y3i = t1i + t3r;
        float c1, s1, c2, s2, c3, s3;
        rot3(stw1 * (float)(j + m * q4), c1, s1, c2, s2, c3, s3);
        xr[0][m] = y0r;                xi4[0][m] = y0i;
        xr[1][m] = y1r * c1 - y1i * s1; xi4[1][m] = y1r * s1 + y1i * c1;
        xr[2][m] = y2r * c2 - y2i * s2; xi4[2][m] = y2r * s2 + y2i * c2;
        xr[3][m] = y3r * c3 - y3i * s3; xi4[3][m] = y3r * s3 + y3i * c3;
      }
      float c1, s1, c2, s2, c3, s3;          // layer 2: stage lq-2, j2 = j
      rot3(stw2 * (float)j, c1, s1, c2, s2, c3, s3);
      #pragma unroll
      for (int k = 0; k < 4; ++k) {
        float t0r = xr[k][0] + xr[k][2], t0i = xi4[k][0] + xi4[k][2];
        float t1r = xr[k][0] - xr[k][2], t1i = xi4[k][0] - xi4[k][2];
        float t2r = xr[k][1] + xr[k][3], t2i = xi4[k][1] + xi4[k][3];
        float t3r = xr[k][1] - xr[k][3], t3i = xi4[k][1] - xi4[k][3];
        float y0r = t0r + t2r, y0i = t0i + t2i;
        float y1r = t1r + t3i, y1i = t1i - t3r;
        float y2r = t0r - t2r, y2i = t0i - t2i;
        float y3r = t1r - t3i, y3i = t1i + t3r;
        const int i0 = base + k * q;
        zr[PAD(i0         )] = y0r;            zi[PAD(i0         )] = y0i;
        zr[PAD(i0 +     q4)] = y1r*c1 - y1i*s1; zi[PAD(i0 +     q4)] = y1r*s1 + y1i*c1;
        zr[PAD(i0 + 2 * q4)] = y2r*c2 - y2i*s2; zi[PAD(i0 + 2 * q4)] = y2r*s2 + y2i*c2;
        zr[PAD(i0 + 3 * q4)] = y3r*c3 - y3i*s3; zi[PAD(i0 + 3 * q4)] = y3r*s3 + y3i*c3;
      }
    }
    __syncthreads();
  }
  // final stage lq=0: q=1, j=0 -> twiddle-free radix-4
  for (int b = tid; b < NFFT / 4; b += NT) {
    const int i0 = b << 2;
    float a0r = zr[PAD(i0)],     a0i = zi[PAD(i0)];
    float a1r = zr[PAD(i0 + 1)], a1i = zi[PAD(i0 + 1)];
    float a2r = zr[PAD(i0 + 2)], a2i = zi[PAD(i0 + 2)];
    float a3r = zr[PAD(i0 + 3)], a3i = zi[PAD(i0 + 3)];
    float t0r = a0r + a2r, t0i = a0i + a2i;
    float t1r = a0r - a2r, t1i = a0i - a2i;
    float t2r = a1r + a3r, t2i = a1i + a3i;
    float t3r = a1r - a3r, t3i = a1i - a3i;
    zr[PAD(i0)]     = t0r + t2r; zi[PAD(i0)]     = t0i + t2i;
    zr[PAD(i0 + 1)] = t1r + t3i; zi[PAD(i0 + 1)] = t1i - t3r;
    zr[PAD(i0 + 2)] = t0r - t2r; zi[PAD(i0 + 2)] = t0i - t2i;
    zr[PAD(i0 + 3)] = t1r - t3i; zi[PAD(i0 + 3)] = t1i + t3r;
  }
  __syncthreads();
}

template<int NT>
__device__ __forceinline__ void fft4_inv(float* zr, float* zi, int tid)
{
  // stage lq=0: q=1, j=0 -> twiddle-free
  for (int b = tid; b < NFFT / 4; b += NT) {
    const int i0 = b << 2;
    float u0r = zr[PAD(i0)],     u0i = zi[PAD(i0)];
    float u1r = zr[PAD(i0 + 1)], u1i = zi[PAD(i0 + 1)];
    float u2r = zr[PAD(i0 + 2)], u2i = zi[PAD(i0 + 2)];
    float u3r = zr[PAD(i0 + 3)], u3i = zi[PAD(i0 + 3)];
    float e0r = u0r + u2r, e0i = u0i + u2i;
    float e1r = u0r - u2r, e1i = u0i - u2i;
    float f0r = u1r + u3r, f0i = u1i + u3i;
    float f1r = u1r - u3r, f1i = u1i - u3i;
    zr[PAD(i0)]     = e0r + f0r; zi[PAD(i0)]     = e0i + f0i;
    zr[PAD(i0 + 1)] = e1r - f1i; zi[PAD(i0 + 1)] = e1i + f1r;
    zr[PAD(i0 + 2)] = e0r - f0r; zi[PAD(i0 + 2)] = e0i - f0i;
    zr[PAD(i0 + 3)] = e1r + f1i; zi[PAD(i0 + 3)] = e1i - f1r;
  }
  __syncthreads();
  #pragma unroll
  for (int lq = 2; lq <= 10; lq += 4) {      // fused pair: stage lq then lq+2
    const int q = 1 << lq;
    const int Q = q << 2;
    const float stw1 = 6.2831853071795864769f / (float)(q << 2);   // 2pi/(4q)
    const float stw2 = 6.2831853071795864769f / (float)(Q << 2);   // 2pi/(4Q)
    for (int g = tid; g < NFFT / 16; g += NT) {
      const int j    = g & (q - 1);
      const int base = ((g >> lq) << (lq + 4)) + j;
      float xr[4][4], xi4[4][4];             // [k][m]: pos = base + m*q + k*Q
      #pragma unroll
      for (int k = 0; k < 4; ++k)
        #pragma unroll
        for (int m = 0; m < 4; ++m) {
          const int idx = PAD(base + m * q + k * Q);
          xr[k][m] = zr[idx]; xi4[k][m] = zi[idx];
        }
      {                                       // layer 1: stage lq, j1 = j (all k)
        float c1, s1, c2, s2, c3, s3;
        rot3(stw1 * (float)j, c1, s1, c2, s2, c3, s3);
        #pragma unroll
        for (int k = 0; k < 4; ++k) {
          float u0r = xr[k][0], u0i = xi4[k][0];
          float u1r = xr[k][1]*c1 - xi4[k][1]*s1, u1i = xr[k][1]*s1 + xi4[k][1]*c1;
          float u2r = xr[k][2]*c2 - xi4[k][2]*s2, u2i = xr[k][2]*s2 + xi4[k][2]*c2;
          float u3r = xr[k][3]*c3 - xi4[k][3]*s3, u3i = xr[k][3]*s3 + xi4[k][3]*c3;
          float e0r = u0r + u2r, e0i = u0i + u2i;
          float e1r = u0r - u2r, e1i = u0i - u2i;
          float f0r = u1r + u3r, f0i = u1i + u3i;
          float f1r = u1r - u3r, f1i = u1i - u3i;
          xr[k][0] = e0r + f0r; xi4[k][0] = e0i + f0i;
          xr[k][1] = e1r - f1i; xi4[k][1] = e1i + f1r;
          xr[k][2] = e0r - f0r; xi4[k][2] = e0i - f0i;
          xr[k][3] = e1r + f1i; xi4[k][3] = e1i - f1r;
        }
      }
      #pragma unroll
      for (int m = 0; m < 4; ++m) {           // layer 2: stage lq+2, j2 = j+m*q
        float c1, s1, c2, s2, c3, s3;
        rot3(stw2 * (float)(j + m * q), c1, s1, c2, s2, c3, s3);
        float u0r = xr[0][m], u0i = xi4[0][m];
        float u1r = xr[1][m]*c1 - xi4[1][m]*s1, u1i = xr[1][m]*s1 + xi4[1][m]*c1;
        float u2r = xr[2][m]*c2 - xi4[2][m]*s2, u2i = xr[2][m]*s2 + xi4[2][m]*c2;
        float u3r = xr[3][m]*c3 - xi4[3][m]*s3, u3i = xr[3][m]*s3 + xi4[3][m]*c3;
        float e0r = u0r + u2r, e0i = u0i + u2i;
        float e1r = u0r - u2r, e1i = u0i - u2i;
        float f0r = u1r + u3r, f0i = u1i + u3i;
        float f1r = u1r - u3r, f1i = u1i - u3i;
        const int i0 = base + m * q;
        zr[PAD(i0        )] = e0r + f0r; zi[PAD(i0        )] = e0i + f0i;
        zr[PAD(i0 +     Q)] = e1r - f1i; zi[PAD(i0 +     Q)] = e1i + f1r;
        zr[PAD(i0 + 2 * Q)] = e0r - f0r; zi[PAD(i0 + 2 * Q)] = e0i - f0i;
        zr[PAD(i0 + 3 * Q)] = e1r + f1i; zi[PAD(i0 + 3 * Q)] = e1i - f1r;
      }
    }
    __syncthreads();
  }
}

// depthwise conv3 on a bf16 row, SAME padding (XLA cross-correlation)
__device__ __forceinline__ float conv3b(const u16* __restrict__ row, int t,
                                        float w0, float w1, float w2, float sb)
{
  float l = (t > 0)         ? bf2f(row[t - 1]) : 0.0f;
  float c = bf2f(row[t]);
  float r = (t < L_SEQ - 1) ? bf2f(row[t + 1]) : 0.0f;
  return w0 * l + w1 * c + w2 * r + sb;
}

// ===========================================================================
// Prep kernels
// ===========================================================================
__global__ __launch_bounds__(256)
void cast_bf16_kernel(const float* __restrict__ in, u16* __restrict__ out, int n4)
{
  int i = blockIdx.x * 256 + threadIdx.x;
  if (i < n4) {
    float4 v = ((const float4*)in)[i];
    U16x4 w; w.x = f2bf(v.x); w.y = f2bf(v.y); w.z = f2bf(v.z); w.w = f2bf(v.w);
    ((U16x4*)out)[i] = w;
  }
}

__global__ __launch_bounds__(256)
void transpose_cast_kernel(const float* __restrict__ in, u16* __restrict__ out,
                           int K, int N)   // in [K][N] fp32 -> out [N][K] bf16
{
  __shared__ u16 tile[32][33];
  const int n0 = blockIdx.x * 32, k0 = blockIdx.y * 32;
  const int tx = threadIdx.x & 31, ty = threadIdx.x >> 5;
  #pragma unroll
  for (int i = 0; i < 32; i += 8)
    tile[ty + i][tx] = f2bf(in[(size_t)(k0 + ty + i) * N + n0 + tx]);
  __syncthreads();
  #pragma unroll
  for (int i = 0; i < 32; i += 8)
    out[(size_t)(n0 + ty + i) * K + k0 + tx] = tile[tx][ty + i];
}

__global__ __launch_bounds__(256)
void transpose_v_kernel(const u16* __restrict__ vb, u16* __restrict__ out)
{
  __shared__ u16 t2[64][65];
  const int m0 = blockIdx.x * 64, f0 = blockIdx.y * 64;
  const int tx = threadIdx.x & 63, ty = threadIdx.x >> 6;
  #pragma unroll
  for (int i = 0; i < 64; i += 4)
    t2[ty + i][tx] = vb[(size_t)(f0 + ty + i) * (2 * NFFT) + m0 + tx];
  __syncthreads();
  #pragma unroll
  for (int i = 0; i < 64; i += 4)
    out[(size_t)(m0 + ty + i) * F_DIM + f0 + tx] = t2[tx][ty + i];
}

// ===========================================================================
// MFMA GEMM (unchanged from round 3, verified)
// ===========================================================================
template<int N_DIM, int K_DIM, int WMODE>
__global__ __launch_bounds__(256)
void mfma_gemm_kernel(const u16* __restrict__ A, const u16* __restrict__ B,
                      const float* __restrict__ bias, void* __restrict__ Cv)
{
  constexpr int BK = 64;
  __shared__ u16 As[128 * BK];
  __shared__ u16 Bs[128 * BK];
  const int tid  = threadIdx.x;
  const int lane = tid & 63;
  const int wid  = tid >> 6;
  const int m0 = blockIdx.x * 128;
  const int n0 = blockIdx.y * 128;

  const u16* aPtr[4]; const u16* bPtr[4];
  #pragma unroll
  for (int i = 0; i < 4; ++i) {
    const int g = tid + (i << 8);
    aPtr[i] = A + (size_t)(m0 + (g >> 3)) * K_DIM + ((g & 7) << 3);
    bPtr[i] = B + (size_t)(n0 + (g >> 3)) * K_DIM + ((g & 7) << 3);
  }

  const int wm = (wid & 1) << 6;
  const int wn = (wid >> 1) << 6;
  int aoff[4], boff[4];
  #pragma unroll
  for (int f = 0; f < 4; ++f) {
    aoff[f] = (wm + f * 16 + (lane & 15)) * BK + ((lane >> 4) << 3);
    boff[f] = (wn + f * 16 + (lane & 15)) * BK + ((lane >> 4) << 3);
  }

  f32x4 acc[4][4];
  #pragma unroll
  for (int i = 0; i < 4; ++i)
    #pragma unroll
    for (int j = 0; j < 4; ++j)
      acc[i][j] = (f32x4){0.f, 0.f, 0.f, 0.f};

  for (int k0 = 0; k0 < K_DIM; k0 += BK) {
    #pragma unroll
    for (int i = 0; i < 4; ++i) {
      __builtin_amdgcn_global_load_lds(
          (const __attribute__((address_space(1))) void*)aPtr[i],
          (__attribute__((address_space(3))) void*)&As[(((wid << 6) + (i << 8)) << 3)],
          16, 0, 0);
      aPtr[i] += BK;
    }
    #pragma unroll
    for (int i = 0; i < 4; ++i) {
      __builtin_amdgcn_global_load_lds(
          (const __attribute__((address_space(1))) void*)bPtr[i],
          (__attribute__((address_space(3))) void*)&Bs[(((wid << 6) + (i << 8)) << 3)],
          16, 0, 0);
      bPtr[i] += BK;
    }
    __syncthreads();
    #pragma unroll
    for (int kk = 0; kk < 2; ++kk) {
      bf16x8 af[4], bg[4];
      #pragma unroll
      for (int f = 0; f < 4; ++f) af[f] = *(const bf16x8*)&As[aoff[f] + kk * 32];
      #pragma unroll
      for (int f = 0; f < 4; ++f) bg[f] = *(const bf16x8*)&Bs[boff[f] + kk * 32];
      #pragma unroll
      for (int fm = 0; fm < 4; ++fm)
        #pragma unroll
        for (int fn = 0; fn < 4; ++fn)
          acc[fm][fn] = __builtin_amdgcn_mfma_f32_16x16x32_bf16(
              af[fm], bg[fn], acc[fm][fn], 0, 0, 0);
    }
    __syncthreads();
  }

  if (WMODE == 0) {
    u16* C = (u16*)Cv;
    const int b = m0 >> 13;
    const int tbase = (m0 & (L_SEQ - 1)) + wm + ((lane >> 4) << 2);
    #pragma unroll
    for (int fn = 0; fn < 4; ++fn) {
      const int n = n0 + wn + fn * 16 + (lane & 15);
      const float bv = bias[n];
      u16* row = C + ((size_t)b * N_DIM + n) * L_SEQ;
      #pragma unroll
      for (int fm = 0; fm < 4; ++fm) {
        f32x4 v = acc[fm][fn];
        U16x4 w;
        w.x = f2bf(v[0] + bv); w.y = f2bf(v[1] + bv);
        w.z = f2bf(v[2] + bv); w.w = f2bf(v[3] + bv);
        *(U16x4*)&row[tbase + fm * 16] = w;
      }
    }
  } else {
    float* C = (float*)Cv;
    #pragma unroll
    for (int fn = 0; fn < 4; ++fn) {
      const int n = n0 + wn + fn * 16 + (lane & 15);
      const float bv = bias[n];
      #pragma unroll
      for (int fm = 0; fm < 4; ++fm) {
        const int mb = m0 + wm + fm * 16 + ((lane >> 4) << 2);
        f32x4 v = acc[fm][fn];
        #pragma unroll
        for (int r = 0; r < 4; ++r)
          C[(size_t)(mb + r) * N_DIM + n] = v[r] + bv;
      }
    }
  }
}

// ===========================================================================
// Kernel A: filter MLP (unchanged, verified)
// ===========================================================================
__global__ __launch_bounds__(256)
void filter_gen_kernel(const float* __restrict__ w1, const float* __restrict__ b1,
                       const float* __restrict__ w2, const float* __restrict__ b2,
                       const float* __restrict__ decay, float* __restrict__ h_t)
{
  __shared__ float hid[64][65];
  const int tid  = threadIdx.x;
  const int tau0 = blockIdx.x * 64;
  const int c0   = blockIdx.y * 256;
  {
    const int r = tid & 63;
    const int tb = tid >> 6;
    const float w1v0 = w1[r];
    const float b1v = b1[r];
    float w1c[4], w1s[4];
    #pragma unroll
    for (int p = 0; p < 4; ++p) { w1c[p] = w1[(1 + p) * 64 + r]; w1s[p] = w1[(5 + p) * 64 + r]; }
    #pragma unroll
    for (int i = 0; i < 16; ++i) {
      const int tl = tb + i * 4;
      const int tau = tau0 + tl;
      const float off = (tau < L_SEQ) ? (float)tau : (float)(tau - NFFT);
      float acc = b1v + off * (1.0f / 8192.0f) * w1v0;
      #pragma unroll
      for (int p = 0; p < 4; ++p) {
        const double period = 4.0 + (8188.0 * p) / 3.0;
        const float freq = (float)(6.283185307179586476925287 / period);
        float sp, cp;
        sincosf(off * freq, &sp, &cp);
        acc += cp * w1c[p] + sp * w1s[p];
      }
      hid[r][tl] = sinf(acc);
    }
  }
  __syncthreads();

  const int tx = tid & 63;
  const int ty = tid >> 6;
  const int taug = tau0 + tx;
  const float mt = (taug < L_SEQ) ? (float)taug * (1.0f / 8191.0f)
                                  : (float)(NFFT - 1 - taug) * (1.0f / 8191.0f);
  const int cbase = c0 + ty * 64;
  for (int cb = 0; cb < 8; ++cb) {
    const int c8 = cbase + cb * 8;
    float acc[8];
    #pragma unroll
    for (int jj = 0; jj < 8; ++jj) acc[jj] = b2[c8 + jj];
    for (int rr = 0; rr < 64; ++rr) {
      const float hv = hid[rr][tx];
      const float4 wa = *(const float4*)&w2[rr * 1536 + c8];
      const float4 wb = *(const float4*)&w2[rr * 1536 + c8 + 4];
      acc[0] += hv * wa.x; acc[1] += hv * wa.y; acc[2] += hv * wa.z; acc[3] += hv * wa.w;
      acc[4] += hv * wb.x; acc[5] += hv * wb.y; acc[6] += hv * wb.z; acc[7] += hv * wb.w;
    }
    #pragma unroll
    for (int jj = 0; jj < 8; ++jj) {
      const int c = c8 + jj;
      const float dec = __expf(-mt * fabsf(decay[c]));
      h_t[(size_t)c * NFFT + taug] = acc[jj] * dec;
    }
  }
}

// ===========================================================================
// Kernel B: filter spectra IN PLACE (fp32 row -> bf16x2 spectrum; bias folded)
// ===========================================================================
__global__ __launch_bounds__(512)
void filter_fft_kernel(float* __restrict__ hH, const float* __restrict__ bias)
{
  __shared__ float zr[NPAD];
  __shared__ float zi[NPAD];
  const int row = blockIdx.x;
  const int tid = threadIdx.x;
  float* h = hH + (size_t)row * NFFT;
  for (int t = tid; t < NFFT; t += 512) { zr[PAD(t)] = h[t]; zi[PAD(t)] = 0.0f; }
  __syncthreads();
  fft4_fwd<512>(zr, zi, tid);
  const float bo = bias[row];
  const float s = 1.0f / (float)NFFT;
  __hip_bfloat162* out2 = (__hip_bfloat162*)h;
  for (int p = tid; p < NFFT; p += 512) {
    __hip_bfloat162 w;
    w.x = __float2bfloat16((zr[PAD(p)] + bo) * s);
    w.y = __float2bfloat16(zi[PAD(p)] * s);
    out2[p] = w;
  }
}

// ===========================================================================
// Kernel C: fused shortconv + 2x (FFT conv + gate); bf16 in, bf16 v rows out
// ===========================================================================
__global__ __launch_bounds__(512)
void fftconv_kernel(const u16* __restrict__ up, float* __restrict__ hH,
                    const float* __restrict__ sw, const float* __restrict__ sb)
{
  __shared__ float zr[NPAD];
  __shared__ float zi[NPAD];
  const int f = blockIdx.x;
  const int tid = threadIdx.x;

  {
    const u16* u0 = up + (size_t)(0 * C_IN + f) * L_SEQ;
    const u16* u1 = up + (size_t)(1 * C_IN + f) * L_SEQ;
    const float vw0 = sw[f], vw1 = sw[C_IN + f], vw2 = sw[2 * C_IN + f];
    const float vb = sb[f];
    for (int t = tid; t < L_SEQ; t += 512) {
      zr[PAD(t)] = conv3b(u0, t, vw0, vw1, vw2, vb);
      zi[PAD(t)] = conv3b(u1, t, vw0, vw1, vw2, vb);
    }
    for (int t = L_SEQ + tid; t < NFFT; t += 512) { zr[PAD(t)] = 0.0f; zi[PAD(t)] = 0.0f; }
  }
  __syncthreads();

  for (int o = 0; o < NORD; ++o) {
    fft4_fwd<512>(zr, zi, tid);
    {
      const __hip_bfloat162* H =
          (const __hip_bfloat162*)(hH + (size_t)(o * F_DIM + f) * NFFT);
      for (int p = tid; p < NFFT; p += 512) {
        const __hip_bfloat162 h2 = H[p];
        const float hr = __bfloat162float(h2.x), hi = __bfloat162float(h2.y);
        const int ip = PAD(p);
        const float ar = zr[ip], ai = zi[ip];
        zr[ip] = ar * hr - ai * hi;
        zi[ip] = ar * hi + ai * hr;
      }
    }
    __syncthreads();
    fft4_inv<512>(zr, zi, tid);

    const int c = (o + 1) * F_DIM + f;
    const u16* x0 = up + (size_t)(0 * C_IN + c) * L_SEQ;
    const u16* x1 = up + (size_t)(1 * C_IN + c) * L_SEQ;
    const float xw0 = sw[c], xw1 = sw[C_IN + c], xw2 = sw[2 * C_IN + c];
    const float xb = sb[c];
    if (o == 0) {
      for (int t = tid; t < L_SEQ; t += 512) {
        zr[PAD(t)] *= conv3b(x0, t, xw0, xw1, xw2, xb);
        zi[PAD(t)] *= conv3b(x1, t, xw0, xw1, xw2, xb);
      }
      for (int t = L_SEQ + tid; t < NFFT; t += 512) { zr[PAD(t)] = 0.0f; zi[PAD(t)] = 0.0f; }
      __syncthreads();
    } else {
      u16* v01 = (u16*)(hH + (size_t)f * NFFT);   // row f consumed at o=0
      for (int t = tid; t < L_SEQ; t += 512) {
        v01[t]         = f2bf(zr[PAD(t)] * conv3b(x0, t, xw0, xw1, xw2, xb));
        v01[L_SEQ + t] = f2bf(zi[PAD(t)] * conv3b(x1, t, xw0, xw1, xw2, xb));
      }
    }
  }
}

// ===========================================================================
extern "C" void kernel_launch(void* const* d_in, const int* in_sizes, int n_in,
                              void* d_out, int out_size, void* d_ws, size_t ws_size,
                              hipStream_t stream)
{
  (void)in_sizes; (void)n_in; (void)out_size; (void)ws_size;
  const float* u     = (const float*)d_in[0];
  const float* fw1   = (const float*)d_in[1];
  const float* fb1   = (const float*)d_in[2];
  const float* fw2   = (const float*)d_in[3];
  const float* fb2   = (const float*)d_in[4];
  const float* decay = (const float*)d_in[5];
  const float* bias  = (const float*)d_in[6];
  const float* ipw   = (const float*)d_in[7];
  const float* ipb   = (const float*)d_in[8];
  const float* sw    = (const float*)d_in[9];
  const float* sb    = (const float*)d_in[10];
  const float* ow    = (const float*)d_in[11];
  const float* ob    = (const float*)d_in[12];
  float* out = (float*)d_out;

  char* ws = (char*)d_ws;
  u16*   up_t  = (u16*)(ws);                                // 75,497,472 B
  float* hH    = (float*)(ws + 75497472);                   // 100,663,296 B
  u16*   u_bf  = (u16*)(ws + 176160768);                    // 25,165,824 B
  u16*   ipw_t = (u16*)(ws + 201326592);                    // 3,538,944 B
  u16*   ow_t  = (u16*)(ws + 204865536);                    // 1,179,648 B
  u16*   vt_t  = (u16*)(ws + 206045184);                    // 25,165,824 B

  cast_bf16_kernel<<<dim3(12288), 256, 0, stream>>>(u, u_bf, (2 * L_SEQ * D_DIM) / 4);
  transpose_cast_kernel<<<dim3(C_IN / 32, D_DIM / 32), 256, 0, stream>>>(ipw, ipw_t, D_DIM, C_IN);
  transpose_cast_kernel<<<dim3(D_DIM / 32, F_DIM / 32), 256, 0, stream>>>(ow, ow_t, F_DIM, D_DIM);

  filter_gen_kernel<<<dim3(NFFT / 64, 1536 / 256), 256, 0, stream>>>(fw1, fb1, fw2, fb2, decay, hH);
  filter_fft_kernel<<<dim3(NORD * F_DIM), 512, 0, stream>>>(hH, bias);

  mfma_gemm_kernel<C_IN, D_DIM, 0><<<dim3(128, C_IN / 128), 256, 0, stream>>>(u_bf, ipw_t, ipb, up_t);
  fftconv_kernel<<<dim3(F_DIM), 512, 0, stream>>>(up_t, hH, sw, sb);
  transpose_v_kernel<<<dim3(NFFT / 64, F_DIM / 64), 256, 0, stream>>>((const u16*)hH, vt_t);
  mfma_gemm_kernel<D_DIM, F_DIM, 1><<<dim3(128, D_DIM / 128), 256, 0, stream>>>(vt_t, ow_t, ob, out);
}